// Round 8
// baseline (820.539 us; speedup 1.0000x reference)
//
#include <hip/hip_runtime.h>
#include <hip/hip_bf16.h>

// Geometry (fixed): B=1, C=8, D=H=W=128.
constexpr int HW2 = 16384;
constexpr int DHW = 2097152;

// MFMA staging: LDS cell = 8 ci (bf16, 16 B) at (slot = dz*4+ry, xi).
constexpr int PKG = 13;
constexpr int XT  = 130;  // staged x extent: x = -1 .. 128

typedef short bf16x8 __attribute__((ext_vector_type(8)));  // 8 bf16 = 4 VGPR
typedef float f32x4  __attribute__((ext_vector_type(4)));

__device__ inline unsigned short f2b(float f) {
  __hip_bfloat16 h = __float2bfloat16(f);
  return *(unsigned short*)&h;
}
__device__ inline float b2f(unsigned short u) {
  __hip_bfloat16 h = *(__hip_bfloat16*)&u;
  return __bfloat162float(h);
}

// ---------------------------------------------------------------------------
// Prep: pack w1/w2 into MFMA A-fragment order, bf16, dx-split.
// Slot g = s*4+q interpreted as (dz = g>>2 = s, dy = g&3 = q); dy==3 -> 0.
// ---------------------------------------------------------------------------
__global__ __launch_bounds__(256) void k_prep(
    const float* __restrict__ w1, const float* __restrict__ w2,
    unsigned short* __restrict__ Wpack2, unsigned short* __restrict__ Wpack1,
    float* __restrict__ g_ti, float* __restrict__ g_xi) {
  int i = blockIdx.x * 256 + threadIdx.x;
  if (i < 9216) {
    int j = i & 7;
    int lane = (i >> 3) & 63;
    int Mt = (i >> 9) & 1;
    int g2 = i >> 10;         // dx*3 + s
    int s = g2 % 3, dx = g2 / 3;
    int oc = Mt * 16 + (lane & 15);
    int kr = s * 32 + (lane >> 4) * 8 + j;
    int ci = kr & 7, g = kr >> 3;          // g = s*4 + q
    float w = 0.f;
    if (oc < 27 && (g & 3) < 3) {
      int dzr = g >> 2, dyr = g & 3;
      w = w2[(oc * 8 + ci) * 27 + dzr * 9 + dyr * 3 + dx];
    }
    Wpack2[i] = f2b(w);
  }
  int jj = i - 9216;
  if (jj >= 0 && jj < 4608) {
    int j = jj & 7;
    int lane = (jj >> 3) & 63;
    int g2 = jj >> 9;         // dx*3 + s
    int s = g2 % 3, dx = g2 / 3;
    int oc = lane & 15;
    int kr = s * 32 + (lane >> 4) * 8 + j;
    int ci = kr & 7, g = kr >> 3;
    float w = 0.f;
    if (oc < 8 && (g & 3) < 3) {
      int dzr = g >> 2, dyr = g & 3;
      w = w1[(oc * 8 + ci) * 27 + dzr * 9 + dyr * 3 + dx];
    }
    Wpack1[jj] = f2b(w);
  }
  int gg = i - 13824;
  if (gg >= 0 && gg < 32) {
    float* p = (gg < 8)  ? (g_ti - 8 + gg)
             : (gg < 16) ? (g_ti + (size_t)8 * DHW + (gg - 8))
             : (gg < 24) ? (g_xi - 8 + (gg - 16))
                         : (g_xi + (size_t)8 * DHW + (gg - 24));
    *p = 0.f;
  }
}

// ---------------------------------------------------------------------------
// Transpose x: [ci][z][y][x] fp32 -> [z][y][x][ci] bf16 (xb, for conv1 MFMA)
//                                 and [z][y][x][ci] fp32 (xi, for adapt pass)
// ---------------------------------------------------------------------------
__global__ __launch_bounds__(256) void k_xpose(
    const float* __restrict__ x, unsigned short* __restrict__ xb,
    float* __restrict__ xi) {
  int idx = blockIdx.x * 256 + threadIdx.x;  // voxel
  float f[8];
  unsigned v[4];
#pragma unroll
  for (int p = 0; p < 4; ++p) {
    f[2 * p]     = x[(size_t)(2 * p) * DHW + idx];
    f[2 * p + 1] = x[(size_t)(2 * p + 1) * DHW + idx];
    unsigned lo = f2b(f[2 * p]);
    unsigned hi = f2b(f[2 * p + 1]);
    v[p] = lo | (hi << 16);
  }
  ((uint4*)xb)[idx] = make_uint4(v[0], v[1], v[2], v[3]);
  float4* xo = (float4*)(xi + (size_t)idx * 8);
  xo[0] = make_float4(f[0], f[1], f[2], f[3]);
  xo[1] = make_float4(f[4], f[5], f[6], f[7]);
}

// ---------------------------------------------------------------------------
// Shared conv staging (R7 y-pair, proven): batched-MLP, division-free.
// ---------------------------------------------------------------------------
#define STAGE_ROWS2(srcp)                                                  \
  {                                                                        \
    if (tid < 154) {                                                       \
      if (tid < 130) {                                                     \
        dst[tid * PKG + 12] = make_uint4(0u, 0u, 0u, 0u);                  \
      } else {                                                             \
        int k = tid - 130;                                                 \
        int sl = k >> 1, xih = (k & 1) ? 129 : 0;                          \
        dst[xih * PKG + sl] = make_uint4(0u, 0u, 0u, 0u);                  \
      }                                                                    \
    }                                                                      \
    const int gg = tid >> 7;                                               \
    const int xi_ = (tid & 127) + 1;                                       \
    const int xg_ = xi_ - 1;                                               \
    uint4 sv[6];                                                           \
    bool vld[6];                                                           \
    _Pragma("unroll")                                                      \
    for (int it = 0; it < 6; ++it) {                                       \
      const int g = gg + it * 2;                                           \
      const int dz = g >> 2, ry = g & 3;                                   \
      const int z = z0 + dz - 1, y = y0 + ry - 1;                          \
      vld[it] = ((unsigned)z < 128u) & ((unsigned)y < 128u);               \
      const int zz = vld[it] ? z : z0, yy = vld[it] ? y : y0;              \
      sv[it] = (srcp)[(zz * 128 + yy) * 128 + xg_];                        \
    }                                                                      \
    _Pragma("unroll")                                                      \
    for (int it = 0; it < 6; ++it) {                                       \
      const int g = gg + it * 2;                                           \
      uint4 v = vld[it] ? sv[it] : make_uint4(0u, 0u, 0u, 0u);             \
      dst[xi_ * PKG + g] = v;                                              \
    }                                                                      \
  }

// ---------------------------------------------------------------------------
// Kernel 1: conv3d(x, w1) + bias + ReLU (8 -> 8), implicit-GEMM MFMA.
// y-pair per block; grid 128 z * 64 ypairs = 8192.
// ---------------------------------------------------------------------------
__global__ __launch_bounds__(256, 3) void k_conv1m(
    const unsigned short* __restrict__ xb,
    const unsigned short* __restrict__ Wpack1,
    const float* __restrict__ b1, unsigned short* __restrict__ hb) {
  __shared__ __align__(16) unsigned short T[XT * PKG * 8];
  const int tid  = threadIdx.x;
  const int lane = tid & 63;
  const int wv   = tid >> 6;
  const int logical = (blockIdx.x & 7) * 1024 + (blockIdx.x >> 3);
  const int z0 = logical >> 6;
  const int y0 = (logical & 63) * 2;

  bf16x8 wf[3][3];
  {
    const bf16x8* wp = (const bf16x8*)Wpack1;
#pragma unroll
    for (int dx = 0; dx < 3; ++dx)
#pragma unroll
      for (int s = 0; s < 3; ++s)
        wf[dx][s] = wp[(dx * 3 + s) * 64 + lane];
  }

  const uint4* src = (const uint4*)xb;
  uint4* dst = (uint4*)T;
  STAGE_ROWS2(src);
  __syncthreads();

  f32x4 acc[2][2];  // [r][nt]
#pragma unroll
  for (int r = 0; r < 2; ++r)
#pragma unroll
    for (int nt = 0; nt < 2; ++nt) acc[r][nt] = (f32x4){0.f, 0.f, 0.f, 0.f};

  const int n = lane & 15;
  const int q = lane >> 4;
  const int xbase = wv * 32 + n;

#pragma unroll
  for (int dx = 0; dx < 3; ++dx) {
#pragma unroll
    for (int s = 0; s < 3; ++s) {
      bf16x8 bfr[2][2];
#pragma unroll
      for (int r = 0; r < 2; ++r)
#pragma unroll
        for (int nt = 0; nt < 2; ++nt) {
          int off = ((xbase + nt * 16 + dx) * PKG + (s * 4 + q + r)) * 8;
          bfr[r][nt] = *(const bf16x8*)&T[off];
        }
#pragma unroll
      for (int r = 0; r < 2; ++r)
#pragma unroll
        for (int nt = 0; nt < 2; ++nt)
          acc[r][nt] = __builtin_amdgcn_mfma_f32_16x16x32_bf16(
              wf[dx][s], bfr[r][nt], acc[r][nt], 0, 0, 0);
    }
  }

  if (q < 2) {
#pragma unroll
    for (int r = 0; r < 2; ++r) {
      const int voxrow = (z0 * 128 + y0 + r) * 128;
#pragma unroll
      for (int nt = 0; nt < 2; ++nt) {
        const int vox = voxrow + wv * 32 + nt * 16 + n;
        ushort4 o;
        o.x = f2b(fmaxf(acc[r][nt][0] + b1[q * 4 + 0], 0.f));
        o.y = f2b(fmaxf(acc[r][nt][1] + b1[q * 4 + 1], 0.f));
        o.z = f2b(fmaxf(acc[r][nt][2] + b1[q * 4 + 2], 0.f));
        o.w = f2b(fmaxf(acc[r][nt][3] + b1[q * 4 + 3], 0.f));
        *(ushort4*)(hb + (size_t)vox * 8 + q * 4) = o;
      }
    }
  }
}

// ---------------------------------------------------------------------------
// Kernel 2: conv3d(h, w2) (8 -> 27) + fused L1 norm, implicit-GEMM MFMA.
// y-pair per block; grid 8192.
// ---------------------------------------------------------------------------
__global__ __launch_bounds__(256, 2) void k_conv2(
    const unsigned short* __restrict__ hb,
    const unsigned short* __restrict__ Wpack2,
    unsigned short* __restrict__ wn) {
  __shared__ __align__(16) unsigned short T[XT * PKG * 8];
  const int tid  = threadIdx.x;
  const int lane = tid & 63;
  const int wv   = tid >> 6;
  const int logical = (blockIdx.x & 7) * 1024 + (blockIdx.x >> 3);
  const int z0 = logical >> 6;
  const int y0 = (logical & 63) * 2;

  bf16x8 wf[3][3][2];
  {
    const bf16x8* wp = (const bf16x8*)Wpack2;
#pragma unroll
    for (int dx = 0; dx < 3; ++dx)
#pragma unroll
      for (int s = 0; s < 3; ++s)
#pragma unroll
        for (int mt = 0; mt < 2; ++mt)
          wf[dx][s][mt] = wp[((dx * 3 + s) * 2 + mt) * 64 + lane];
  }

  const uint4* src = (const uint4*)hb;
  uint4* dst = (uint4*)T;
  STAGE_ROWS2(src);
  __syncthreads();

  f32x4 acc[2][2][2];  // [r][nt][mt]
#pragma unroll
  for (int r = 0; r < 2; ++r)
#pragma unroll
    for (int nt = 0; nt < 2; ++nt)
#pragma unroll
      for (int mt = 0; mt < 2; ++mt)
        acc[r][nt][mt] = (f32x4){0.f, 0.f, 0.f, 0.f};

  const int n = lane & 15;
  const int q = lane >> 4;
  const int xbase = wv * 32 + n;

#pragma unroll
  for (int dx = 0; dx < 3; ++dx) {
#pragma unroll
    for (int s = 0; s < 3; ++s) {
      bf16x8 bfr[2][2];
#pragma unroll
      for (int r = 0; r < 2; ++r)
#pragma unroll
        for (int nt = 0; nt < 2; ++nt) {
          int off = ((xbase + nt * 16 + dx) * PKG + (s * 4 + q + r)) * 8;
          bfr[r][nt] = *(const bf16x8*)&T[off];
        }
#pragma unroll
      for (int r = 0; r < 2; ++r)
#pragma unroll
        for (int mt = 0; mt < 2; ++mt)
#pragma unroll
          for (int nt = 0; nt < 2; ++nt)
            acc[r][nt][mt] = __builtin_amdgcn_mfma_f32_16x16x32_bf16(
                wf[dx][s][mt], bfr[r][nt], acc[r][nt][mt], 0, 0, 0);
    }
  }

#pragma unroll
  for (int r = 0; r < 2; ++r) {
    const int voxrow = (z0 * 128 + y0 + r) * 128;
#pragma unroll
    for (int nt = 0; nt < 2; ++nt) {
      float ns = 0.f;
#pragma unroll
      for (int rr = 0; rr < 4; ++rr) ns += fabsf(acc[r][nt][0][rr]);
#pragma unroll
      for (int rr = 0; rr < 4; ++rr) {
        int oc = 16 + q * 4 + rr;
        ns += (oc < 27) ? fabsf(acc[r][nt][1][rr]) : 0.f;
      }
      ns += __shfl_xor(ns, 16);
      ns += __shfl_xor(ns, 32);
      float sc = 1.f / fmaxf(ns, 1e-12f);
      const int vox = voxrow + wv * 32 + nt * 16 + n;
#pragma unroll
      for (int rr = 0; rr < 4; ++rr) {
        int oc = q * 4 + rr;
        wn[(size_t)oc * DHW + vox] = f2b(acc[r][nt][0][rr] * sc);
      }
#pragma unroll
      for (int rr = 0; rr < 4; ++rr) {
        int oc = 16 + q * 4 + rr;
        if (oc < 27)
          wn[(size_t)oc * DHW + vox] = f2b(acc[r][nt][1][rr] * sc);
      }
    }
  }
}

// ---------------------------------------------------------------------------
// Kernel 3 (R8): persistent, software-pipelined LDS-tiled adaptive conv.
// Grid = 512 blocks (2/CU); block owns 8 y-adjacent tiles (same tz ->
// consecutive tiles share 8/16 staged rows in L2). Per tile (T3 2-phase):
//   issue loads(next tile: 16 uint4 rows + 27 wn words) -> compute(cur from
//   LDS) -> barrier -> ds_write(next) -> barrier.
// HBM latency hides under the ~3k-cy compute phase; wn regs ping-pong
// (wnA/wnB static names), stg regs live through compute by design.
// Swizzle / read / fma / store bodies identical to R7's proven adapt4.
// ---------------------------------------------------------------------------
__device__ inline int swzb(int off) { return off ^ (((off >> 7) & 7) << 4); }

#define AD_ISSUE_X(ty_)                                                   \
  {                                                                       \
    const int ys0_ = 2 * (ty_) - 1;                                       \
    _Pragma("unroll")                                                     \
    for (int c = 0; c < 16; ++c) {                                        \
      const int ys_ = min(max(ys0_ + (c & 3), 0), 127);                   \
      stg[c] =                                                            \
          ((const uint4*)(in + (size_t)(zs4[c >> 2] * 128 + ys_) * 1024)) \
              [tid];                                                      \
    }                                                                     \
  }

#define AD_ISSUE_WN(W_, ty_)                                              \
  {                                                                       \
    const int vox_ = (zrow + 2 * (ty_) + yl) * 128 + xg;                  \
    _Pragma("unroll")                                                     \
    for (int k2 = 0; k2 < 27; ++k2)                                       \
      W_[k2] = *(const unsigned*)(wn + (size_t)k2 * DHW + vox_);          \
  }

#define AD_DSW()                                                          \
  {                                                                       \
    _Pragma("unroll")                                                     \
    for (int c = 0; c < 16; ++c)                                          \
      *(uint4*)(S + c * 4224 + woff) = stg[c];                            \
  }

#define AD_COMPUTE(W_, ty_)                                               \
  {                                                                       \
    const int yout_ = 2 * (ty_) + yl;                                     \
    const int vox0_ = (zrow + yout_) * 128 + xg;                          \
    f32x4 a0A = (f32x4){0.f, 0.f, 0.f, 0.f};                              \
    f32x4 a0B = (f32x4){0.f, 0.f, 0.f, 0.f};                              \
    f32x4 a1A = (f32x4){0.f, 0.f, 0.f, 0.f};                              \
    f32x4 a1B = (f32x4){0.f, 0.f, 0.f, 0.f};                              \
    _Pragma("unroll")                                                     \
    for (int g = 0; g < 9; ++g) {                                         \
      const int dzp_ = g / 3, dyp_ = g % 3;                               \
      const char* R_ = S + ((zl + dzp_) * 4 + (yl + dyp_)) * 4224;        \
      f32x4 W4[4][2];                                                     \
      _Pragma("unroll")                                                   \
      for (int p = 0; p < 4; ++p)                                         \
        _Pragma("unroll")                                                 \
        for (int h = 0; h < 2; ++h)                                       \
          W4[p][h] = *(const f32x4*)(R_ + soff[p][h]);                    \
      const bool val_ =                                                   \
          zok[dzp_] & ((unsigned)(yout_ + dyp_ - 1) < 128u);              \
      _Pragma("unroll")                                                   \
      for (int dxi = 0; dxi < 3; ++dxi) {                                 \
        const unsigned u_ = W_[g * 3 + dxi];                              \
        const float wl_ =                                                 \
            val_ ? b2f((unsigned short)(u_ & 0xffffu)) : 0.f;             \
        const float wh_ = val_ ? b2f((unsigned short)(u_ >> 16)) : 0.f;   \
        _Pragma("unroll")                                                 \
        for (int c = 0; c < 4; ++c) {                                     \
          a0A[c] = fmaf(W4[dxi][0][c], wl_, a0A[c]);                      \
          a0B[c] = fmaf(W4[dxi][1][c], wl_, a0B[c]);                      \
          a1A[c] = fmaf(W4[dxi + 1][0][c], wh_, a1A[c]);                  \
          a1B[c] = fmaf(W4[dxi + 1][1][c], wh_, a1B[c]);                  \
        }                                                                 \
      }                                                                   \
    }                                                                     \
    if (FINAL) {                                                          \
      _Pragma("unroll")                                                   \
      for (int c = 0; c < 4; ++c) {                                       \
        *(float2*)(out + (size_t)c * DHW + vox0_) =                       \
            make_float2(a0A[c], a1A[c]);                                  \
        *(float2*)(out + (size_t)(c + 4) * DHW + vox0_) =                 \
            make_float2(a0B[c], a1B[c]);                                  \
      }                                                                   \
    } else {                                                              \
      f32x4* op_ = (f32x4*)(out + (size_t)vox0_ * 8);                     \
      op_[0] = a0A;                                                       \
      op_[1] = a0B;                                                       \
      op_[2] = a1A;                                                       \
      op_[3] = a1B;                                                       \
    }                                                                     \
  }

template <int FINAL>
__global__ __launch_bounds__(256, 2) void k_adapt5(
    const float* __restrict__ in, const unsigned short* __restrict__ wn,
    float* __restrict__ out) {
  __shared__ __align__(16) char S[16 * 4224];
  const int tid = threadIdx.x;
  const int wv = tid >> 6, lane = tid & 63;
  const int zl = wv >> 1, yl = wv & 1;
  const int xg = lane * 2;

  // XCD-chunked bijective swizzle on 512 persistent blocks: XCD k owns a
  // contiguous 64-block band (512 contiguous tiles).
  const int logical_b = ((blockIdx.x & 7) << 6) + (blockIdx.x >> 3);
  const int tz = logical_b >> 3;          // tile-z (all 8 tiles share it)
  const int ty0 = (logical_b & 7) * 8;    // first tile-y

  int zs4[4];
#pragma unroll
  for (int d = 0; d < 4; ++d) zs4[d] = min(max(2 * tz - 1 + d, 0), 127);
  bool zok[3];
#pragma unroll
  for (int d = 0; d < 3; ++d)
    zok[d] = (unsigned)(2 * tz + zl + d - 1) < 128u;
  const int zrow = (2 * tz + zl) * 128;

  const int woff = swzb(32 + tid * 16);
  int soff[4][2];
#pragma unroll
  for (int p = 0; p < 4; ++p)
#pragma unroll
    for (int h = 0; h < 2; ++h)
      soff[p][h] = swzb((xg + p) * 32 + h * 16);

  // zero x-halo slots once (bytes [0,32) and [4128,4160) are swzb
  // fixed-points, and AD_DSW never touches them)
  if (tid < 64) {
    const int row = tid >> 2, part = tid & 3;
    const int off = (part < 2) ? part * 16 : (4128 + (part - 2) * 16);
    *(uint4*)(S + row * 4224 + off) = make_uint4(0u, 0u, 0u, 0u);
  }

  uint4 stg[16];
  unsigned wnA[27], wnB[27];

  // prologue: stage tile 0
  AD_ISSUE_X(ty0);
  AD_ISSUE_WN(wnA, ty0);
  AD_DSW();
  __syncthreads();

#pragma unroll 1
  for (int k = 0; k < 4; ++k) {
    const int tyA = ty0 + 2 * k;
    const int tyB = tyA + 1;
    const int tyC = (k < 3) ? (tyA + 2) : tyB;  // harmless dup on last

    AD_ISSUE_X(tyB);
    AD_ISSUE_WN(wnB, tyB);
    AD_COMPUTE(wnA, tyA);
    __syncthreads();
    AD_DSW();
    __syncthreads();

    AD_ISSUE_X(tyC);
    AD_ISSUE_WN(wnA, tyC);
    AD_COMPUTE(wnB, tyB);
    __syncthreads();
    AD_DSW();
    __syncthreads();
  }
}

// ---------------------------------------------------------------------------
extern "C" void kernel_launch(void* const* d_in, const int* in_sizes, int n_in,
                              void* d_out, int out_size, void* d_ws, size_t ws_size,
                              hipStream_t stream) {
  const float* x  = (const float*)d_in[0];
  const float* w1 = (const float*)d_in[1];
  const float* b1 = (const float*)d_in[2];
  const float* w2 = (const float*)d_in[3];
  float* out = (float*)d_out;

  // Workspace (~236 MiB + pads):
  //   [0,   64M): xb(32M)+hb(32M) bf16; reused as ti = ws+256 (64M fp32)
  //   [64M+4K, 172M+4K): wn bf16 planar (27 x DHW)
  //   [172M+12K, 236M+12K): xi fp32 interleaved
  //   then Wpack2, Wpack1.
  char* ws = (char*)d_ws;
  unsigned short* xb = (unsigned short*)ws;
  unsigned short* hb = (unsigned short*)(ws + (size_t)8 * DHW * 2);
  float* ti = (float*)(ws + 256);  // aliases xb+hb (both dead before adapt)
  unsigned short* wn = (unsigned short*)(ws + (size_t)16 * DHW * 2 + 4096);
  float* xi = (float*)(ws + (size_t)16 * DHW * 2 + 4096 +
                       (size_t)27 * DHW * 2 + 8192);
  unsigned short* Wpack2 =
      (unsigned short*)((char*)xi + (size_t)8 * DHW * 4 + 16384);
  unsigned short* Wpack1 = Wpack2 + 9216;

  dim3 blk(256);
  k_prep<<<55, blk, 0, stream>>>(w1, w2, Wpack2, Wpack1, ti, xi);
  k_xpose<<<DHW / 256, blk, 0, stream>>>(x, xb, xi);
  k_conv1m<<<128 * 64, blk, 0, stream>>>(xb, Wpack1, b1, hb);
  k_conv2<<<128 * 64, blk, 0, stream>>>(hb, Wpack2, wn);
  // adaptive ping-pong on interleaved fp32: xi -> ti -> xi -> out (planar)
  k_adapt5<0><<<512, blk, 0, stream>>>(xi, wn, ti);
  k_adapt5<0><<<512, blk, 0, stream>>>(ti, wn, xi);
  k_adapt5<1><<<512, blk, 0, stream>>>(xi, wn, out);
}

// Round 9
// 359.606 us; speedup vs baseline: 2.2818x; 2.2818x over previous
//
#include <hip/hip_runtime.h>
#include <hip/hip_bf16.h>

// Geometry (fixed): B=1, C=8, D=H=W=128.
constexpr int HW2 = 16384;
constexpr int DHW = 2097152;

// MFMA staging: LDS cell = 8 ci (bf16, 16 B) at (slot = dz*4+ry, xi).
constexpr int PKG = 13;
constexpr int XT  = 130;  // staged x extent: x = -1 .. 128

typedef short bf16x8 __attribute__((ext_vector_type(8)));  // 8 bf16 = 4 VGPR
typedef float f32x4  __attribute__((ext_vector_type(4)));

__device__ inline unsigned short f2b(float f) {
  __hip_bfloat16 h = __float2bfloat16(f);
  return *(unsigned short*)&h;
}
__device__ inline float b2f(unsigned short u) {
  __hip_bfloat16 h = *(__hip_bfloat16*)&u;
  return __bfloat162float(h);
}

// ---------------------------------------------------------------------------
// Prep: pack w1/w2 into MFMA A-fragment order, bf16, dx-split.
// Slot g = s*4+q interpreted as (dz = g>>2 = s, dy = g&3 = q); dy==3 -> 0.
// ---------------------------------------------------------------------------
__global__ __launch_bounds__(256) void k_prep(
    const float* __restrict__ w1, const float* __restrict__ w2,
    unsigned short* __restrict__ Wpack2, unsigned short* __restrict__ Wpack1,
    float* __restrict__ g_ti, float* __restrict__ g_xi) {
  int i = blockIdx.x * 256 + threadIdx.x;
  if (i < 9216) {
    int j = i & 7;
    int lane = (i >> 3) & 63;
    int Mt = (i >> 9) & 1;
    int g2 = i >> 10;         // dx*3 + s
    int s = g2 % 3, dx = g2 / 3;
    int oc = Mt * 16 + (lane & 15);
    int kr = s * 32 + (lane >> 4) * 8 + j;
    int ci = kr & 7, g = kr >> 3;          // g = s*4 + q
    float w = 0.f;
    if (oc < 27 && (g & 3) < 3) {
      int dzr = g >> 2, dyr = g & 3;
      w = w2[(oc * 8 + ci) * 27 + dzr * 9 + dyr * 3 + dx];
    }
    Wpack2[i] = f2b(w);
  }
  int jj = i - 9216;
  if (jj >= 0 && jj < 4608) {
    int j = jj & 7;
    int lane = (jj >> 3) & 63;
    int g2 = jj >> 9;         // dx*3 + s
    int s = g2 % 3, dx = g2 / 3;
    int oc = lane & 15;
    int kr = s * 32 + (lane >> 4) * 8 + j;
    int ci = kr & 7, g = kr >> 3;
    float w = 0.f;
    if (oc < 8 && (g & 3) < 3) {
      int dzr = g >> 2, dyr = g & 3;
      w = w1[(oc * 8 + ci) * 27 + dzr * 9 + dyr * 3 + dx];
    }
    Wpack1[jj] = f2b(w);
  }
  int gg = i - 13824;
  if (gg >= 0 && gg < 32) {
    float* p = (gg < 8)  ? (g_ti - 8 + gg)
             : (gg < 16) ? (g_ti + (size_t)8 * DHW + (gg - 8))
             : (gg < 24) ? (g_xi - 8 + (gg - 16))
                         : (g_xi + (size_t)8 * DHW + (gg - 24));
    *p = 0.f;
  }
}

// ---------------------------------------------------------------------------
// Transpose x: [ci][z][y][x] fp32 -> [z][y][x][ci] bf16 (xb, for conv1 MFMA)
//                                 and [z][y][x][ci] fp32 (xi, for adapt pass)
// ---------------------------------------------------------------------------
__global__ __launch_bounds__(256) void k_xpose(
    const float* __restrict__ x, unsigned short* __restrict__ xb,
    float* __restrict__ xi) {
  int idx = blockIdx.x * 256 + threadIdx.x;  // voxel
  float f[8];
  unsigned v[4];
#pragma unroll
  for (int p = 0; p < 4; ++p) {
    f[2 * p]     = x[(size_t)(2 * p) * DHW + idx];
    f[2 * p + 1] = x[(size_t)(2 * p + 1) * DHW + idx];
    unsigned lo = f2b(f[2 * p]);
    unsigned hi = f2b(f[2 * p + 1]);
    v[p] = lo | (hi << 16);
  }
  ((uint4*)xb)[idx] = make_uint4(v[0], v[1], v[2], v[3]);
  float4* xo = (float4*)(xi + (size_t)idx * 8);
  xo[0] = make_float4(f[0], f[1], f[2], f[3]);
  xo[1] = make_float4(f[4], f[5], f[6], f[7]);
}

// ---------------------------------------------------------------------------
// Shared conv staging (R7 y-pair, proven): batched-MLP, division-free.
// ---------------------------------------------------------------------------
#define STAGE_ROWS2(srcp)                                                  \
  {                                                                        \
    if (tid < 154) {                                                       \
      if (tid < 130) {                                                     \
        dst[tid * PKG + 12] = make_uint4(0u, 0u, 0u, 0u);                  \
      } else {                                                             \
        int k = tid - 130;                                                 \
        int sl = k >> 1, xih = (k & 1) ? 129 : 0;                          \
        dst[xih * PKG + sl] = make_uint4(0u, 0u, 0u, 0u);                  \
      }                                                                    \
    }                                                                      \
    const int gg = tid >> 7;                                               \
    const int xi_ = (tid & 127) + 1;                                       \
    const int xg_ = xi_ - 1;                                               \
    uint4 sv[6];                                                           \
    bool vld[6];                                                           \
    _Pragma("unroll")                                                      \
    for (int it = 0; it < 6; ++it) {                                       \
      const int g = gg + it * 2;                                           \
      const int dz = g >> 2, ry = g & 3;                                   \
      const int z = z0 + dz - 1, y = y0 + ry - 1;                          \
      vld[it] = ((unsigned)z < 128u) & ((unsigned)y < 128u);               \
      const int zz = vld[it] ? z : z0, yy = vld[it] ? y : y0;              \
      sv[it] = (srcp)[(zz * 128 + yy) * 128 + xg_];                        \
    }                                                                      \
    _Pragma("unroll")                                                      \
    for (int it = 0; it < 6; ++it) {                                       \
      const int g = gg + it * 2;                                           \
      uint4 v = vld[it] ? sv[it] : make_uint4(0u, 0u, 0u, 0u);             \
      dst[xi_ * PKG + g] = v;                                              \
    }                                                                      \
  }

// ---------------------------------------------------------------------------
// Kernel 1: conv3d(x, w1) + bias + ReLU (8 -> 8), implicit-GEMM MFMA.
// y-pair per block; grid 128 z * 64 ypairs = 8192.
// ---------------------------------------------------------------------------
__global__ __launch_bounds__(256, 3) void k_conv1m(
    const unsigned short* __restrict__ xb,
    const unsigned short* __restrict__ Wpack1,
    const float* __restrict__ b1, unsigned short* __restrict__ hb) {
  __shared__ __align__(16) unsigned short T[XT * PKG * 8];
  const int tid  = threadIdx.x;
  const int lane = tid & 63;
  const int wv   = tid >> 6;
  const int logical = (blockIdx.x & 7) * 1024 + (blockIdx.x >> 3);
  const int z0 = logical >> 6;
  const int y0 = (logical & 63) * 2;

  bf16x8 wf[3][3];
  {
    const bf16x8* wp = (const bf16x8*)Wpack1;
#pragma unroll
    for (int dx = 0; dx < 3; ++dx)
#pragma unroll
      for (int s = 0; s < 3; ++s)
        wf[dx][s] = wp[(dx * 3 + s) * 64 + lane];
  }

  const uint4* src = (const uint4*)xb;
  uint4* dst = (uint4*)T;
  STAGE_ROWS2(src);
  __syncthreads();

  f32x4 acc[2][2];  // [r][nt]
#pragma unroll
  for (int r = 0; r < 2; ++r)
#pragma unroll
    for (int nt = 0; nt < 2; ++nt) acc[r][nt] = (f32x4){0.f, 0.f, 0.f, 0.f};

  const int n = lane & 15;
  const int q = lane >> 4;
  const int xbase = wv * 32 + n;

#pragma unroll
  for (int dx = 0; dx < 3; ++dx) {
#pragma unroll
    for (int s = 0; s < 3; ++s) {
      bf16x8 bfr[2][2];
#pragma unroll
      for (int r = 0; r < 2; ++r)
#pragma unroll
        for (int nt = 0; nt < 2; ++nt) {
          int off = ((xbase + nt * 16 + dx) * PKG + (s * 4 + q + r)) * 8;
          bfr[r][nt] = *(const bf16x8*)&T[off];
        }
#pragma unroll
      for (int r = 0; r < 2; ++r)
#pragma unroll
        for (int nt = 0; nt < 2; ++nt)
          acc[r][nt] = __builtin_amdgcn_mfma_f32_16x16x32_bf16(
              wf[dx][s], bfr[r][nt], acc[r][nt], 0, 0, 0);
    }
  }

  if (q < 2) {
#pragma unroll
    for (int r = 0; r < 2; ++r) {
      const int voxrow = (z0 * 128 + y0 + r) * 128;
#pragma unroll
      for (int nt = 0; nt < 2; ++nt) {
        const int vox = voxrow + wv * 32 + nt * 16 + n;
        ushort4 o;
        o.x = f2b(fmaxf(acc[r][nt][0] + b1[q * 4 + 0], 0.f));
        o.y = f2b(fmaxf(acc[r][nt][1] + b1[q * 4 + 1], 0.f));
        o.z = f2b(fmaxf(acc[r][nt][2] + b1[q * 4 + 2], 0.f));
        o.w = f2b(fmaxf(acc[r][nt][3] + b1[q * 4 + 3], 0.f));
        *(ushort4*)(hb + (size_t)vox * 8 + q * 4) = o;
      }
    }
  }
}

// ---------------------------------------------------------------------------
// Kernel 2: conv3d(h, w2) (8 -> 27) + fused L1 norm, implicit-GEMM MFMA.
// y-pair per block; grid 8192.
// ---------------------------------------------------------------------------
__global__ __launch_bounds__(256, 2) void k_conv2(
    const unsigned short* __restrict__ hb,
    const unsigned short* __restrict__ Wpack2,
    unsigned short* __restrict__ wn) {
  __shared__ __align__(16) unsigned short T[XT * PKG * 8];
  const int tid  = threadIdx.x;
  const int lane = tid & 63;
  const int wv   = tid >> 6;
  const int logical = (blockIdx.x & 7) * 1024 + (blockIdx.x >> 3);
  const int z0 = logical >> 6;
  const int y0 = (logical & 63) * 2;

  bf16x8 wf[3][3][2];
  {
    const bf16x8* wp = (const bf16x8*)Wpack2;
#pragma unroll
    for (int dx = 0; dx < 3; ++dx)
#pragma unroll
      for (int s = 0; s < 3; ++s)
#pragma unroll
        for (int mt = 0; mt < 2; ++mt)
          wf[dx][s][mt] = wp[((dx * 3 + s) * 2 + mt) * 64 + lane];
  }

  const uint4* src = (const uint4*)hb;
  uint4* dst = (uint4*)T;
  STAGE_ROWS2(src);
  __syncthreads();

  f32x4 acc[2][2][2];  // [r][nt][mt]
#pragma unroll
  for (int r = 0; r < 2; ++r)
#pragma unroll
    for (int nt = 0; nt < 2; ++nt)
#pragma unroll
      for (int mt = 0; mt < 2; ++mt)
        acc[r][nt][mt] = (f32x4){0.f, 0.f, 0.f, 0.f};

  const int n = lane & 15;
  const int q = lane >> 4;
  const int xbase = wv * 32 + n;

#pragma unroll
  for (int dx = 0; dx < 3; ++dx) {
#pragma unroll
    for (int s = 0; s < 3; ++s) {
      bf16x8 bfr[2][2];
#pragma unroll
      for (int r = 0; r < 2; ++r)
#pragma unroll
        for (int nt = 0; nt < 2; ++nt) {
          int off = ((xbase + nt * 16 + dx) * PKG + (s * 4 + q + r)) * 8;
          bfr[r][nt] = *(const bf16x8*)&T[off];
        }
#pragma unroll
      for (int r = 0; r < 2; ++r)
#pragma unroll
        for (int mt = 0; mt < 2; ++mt)
#pragma unroll
          for (int nt = 0; nt < 2; ++nt)
            acc[r][nt][mt] = __builtin_amdgcn_mfma_f32_16x16x32_bf16(
                wf[dx][s][mt], bfr[r][nt], acc[r][nt][mt], 0, 0, 0);
    }
  }

#pragma unroll
  for (int r = 0; r < 2; ++r) {
    const int voxrow = (z0 * 128 + y0 + r) * 128;
#pragma unroll
    for (int nt = 0; nt < 2; ++nt) {
      float ns = 0.f;
#pragma unroll
      for (int rr = 0; rr < 4; ++rr) ns += fabsf(acc[r][nt][0][rr]);
#pragma unroll
      for (int rr = 0; rr < 4; ++rr) {
        int oc = 16 + q * 4 + rr;
        ns += (oc < 27) ? fabsf(acc[r][nt][1][rr]) : 0.f;
      }
      ns += __shfl_xor(ns, 16);
      ns += __shfl_xor(ns, 32);
      float sc = 1.f / fmaxf(ns, 1e-12f);
      const int vox = voxrow + wv * 32 + nt * 16 + n;
#pragma unroll
      for (int rr = 0; rr < 4; ++rr) {
        int oc = q * 4 + rr;
        wn[(size_t)oc * DHW + vox] = f2b(acc[r][nt][0][rr] * sc);
      }
#pragma unroll
      for (int rr = 0; rr < 4; ++rr) {
        int oc = 16 + q * 4 + rr;
        if (oc < 27)
          wn[(size_t)oc * DHW + vox] = f2b(acc[r][nt][1][rr] * sc);
      }
    }
  }
}

// ---------------------------------------------------------------------------
// Kernel 3 (R9): LDS-tiled adaptive conv, 512 threads / 1 voxel per thread.
// Same 128x*2y*2z tile and 16-row LDS buffer as the proven R7 adapt4, but
// 8 waves/block -> 16 waves/CU (2x TLP; R7's pipes were all <=50% busy and
// the structure was concurrency-bound). Per-thread state is tiny (acc 8,
// wn 27 ushort, 8 transient staging uint4) -> ~90 VGPR, far from the spill
// cliff that killed R4/R8. Swizzle now ingests off bits 10+ as a conflict
// diagnostic; halo-zero writes wrapped in swzb accordingly. s_setprio(1)
// around the FMA cluster (dephased blocks -> role diversity).
// ---------------------------------------------------------------------------
__device__ inline int swzb(int off) {
  return off ^ ((((off >> 7) ^ (off >> 10)) & 7) << 4);
}

template <int FINAL>
__global__ __launch_bounds__(512, 2) void k_adapt6(
    const float* __restrict__ in, const unsigned short* __restrict__ wn,
    float* __restrict__ out) {
  __shared__ __align__(16) char S[16 * 4224];
  const int tid = threadIdx.x;
  // XCD-chunked bijective swizzle (4096 % 8 == 0): chunk 512.
  const int logical = (blockIdx.x & 7) * 512 + (blockIdx.x >> 3);
  const int ty = logical & 63, tz = logical >> 6;
  const int y0 = ty * 2, z0 = tz * 2;

  // compute role: row r = tid>>7 (0..3), x = tid&127
  const int r = tid >> 7;
  const int zl = r >> 1, yl = r & 1;
  const int x = tid & 127;
  const int zout = z0 + zl, yout = y0 + yl;
  const int vox = (zout * 128 + yout) * 128 + x;

  // staging role: half sh = tid>>8 covers rows 8*sh..8*sh+7; spos = cell.
  const int sh = tid >> 8;
  const int spos = tid & 255;

  // ---- issue staging loads (8 rows x 16 B each; 1 KiB/wave contiguous) ----
  uint4 stg[8];
#pragma unroll
  for (int c = 0; c < 8; ++c) {
    const int row = sh * 8 + c;
    const int zs = min(max(z0 - 1 + (row >> 2), 0), 127);
    const int ys = min(max(y0 - 1 + (row & 3), 0), 127);
    stg[c] = ((const uint4*)(in + (size_t)(zs * 128 + ys) * 1024))[spos];
  }

  // ---- issue all 27 wn loads (2 B, lane-contiguous) before the barrier ----
  unsigned short wnv[27];
#pragma unroll
  for (int k = 0; k < 27; ++k)
    wnv[k] = wn[(size_t)k * DHW + vox];

  // ---- LDS staging writes, swizzled ----
  {
    const int woff = swzb(32 + spos * 16);
#pragma unroll
    for (int c = 0; c < 8; ++c)
      *(uint4*)(S + (sh * 8 + c) * 4224 + woff) = stg[c];
  }
  if (tid < 64) {  // zero x-halo slots 0 (pos=-1) and 129 (pos=128)
    const int row = tid >> 2, part = tid & 3;
    const int off = (part < 2) ? part * 16 : (4128 + (part - 2) * 16);
    *(uint4*)(S + row * 4224 + swzb(off)) = make_uint4(0u, 0u, 0u, 0u);
  }
  __syncthreads();

  int soff[3][2];
#pragma unroll
  for (int p = 0; p < 3; ++p)
#pragma unroll
    for (int h = 0; h < 2; ++h)
      soff[p][h] = swzb((x + p) * 32 + h * 16);

  bool zok[3], yok[3];
#pragma unroll
  for (int d = 0; d < 3; ++d) {
    zok[d] = (unsigned)(zout + d - 1) < 128u;
    yok[d] = (unsigned)(yout + d - 1) < 128u;
  }

  f32x4 aA = (f32x4){0.f, 0.f, 0.f, 0.f};
  f32x4 aB = (f32x4){0.f, 0.f, 0.f, 0.f};

  __builtin_amdgcn_s_setprio(1);
#pragma unroll
  for (int g = 0; g < 9; ++g) {
    const int dzp = g / 3, dyp = g % 3;  // static (full unroll)
    const char* R = S + ((zl + dzp) * 4 + (yl + dyp)) * 4224;
    f32x4 W[3][2];
#pragma unroll
    for (int p = 0; p < 3; ++p)
#pragma unroll
      for (int h = 0; h < 2; ++h)
        W[p][h] = *(const f32x4*)(R + soff[p][h]);
    const bool val = zok[dzp] & yok[dyp];
#pragma unroll
    for (int dxi = 0; dxi < 3; ++dxi) {
      const float w = val ? b2f(wnv[g * 3 + dxi]) : 0.f;
#pragma unroll
      for (int c = 0; c < 4; ++c) {
        aA[c] = fmaf(W[dxi][0][c], w, aA[c]);
        aB[c] = fmaf(W[dxi][1][c], w, aB[c]);
      }
    }
  }
  __builtin_amdgcn_s_setprio(0);

  if (FINAL) {
    // planar fp32 [c][vox] -> d_out; scalar stores, lane-contiguous
#pragma unroll
    for (int c = 0; c < 4; ++c) {
      out[(size_t)c * DHW + vox] = aA[c];
      out[(size_t)(c + 4) * DHW + vox] = aB[c];
    }
  } else {
    // interleaved fp32 [vox][8]
    f32x4* op = (f32x4*)(out + (size_t)vox * 8);
    op[0] = aA;
    op[1] = aB;
  }
}

// ---------------------------------------------------------------------------
extern "C" void kernel_launch(void* const* d_in, const int* in_sizes, int n_in,
                              void* d_out, int out_size, void* d_ws, size_t ws_size,
                              hipStream_t stream) {
  const float* x  = (const float*)d_in[0];
  const float* w1 = (const float*)d_in[1];
  const float* b1 = (const float*)d_in[2];
  const float* w2 = (const float*)d_in[3];
  float* out = (float*)d_out;

  // Workspace (~236 MiB + pads):
  //   [0,   64M): xb(32M)+hb(32M) bf16; reused as ti = ws+256 (64M fp32)
  //   [64M+4K, 172M+4K): wn bf16 planar (27 x DHW)
  //   [172M+12K, 236M+12K): xi fp32 interleaved
  //   then Wpack2, Wpack1.
  char* ws = (char*)d_ws;
  unsigned short* xb = (unsigned short*)ws;
  unsigned short* hb = (unsigned short*)(ws + (size_t)8 * DHW * 2);
  float* ti = (float*)(ws + 256);  // aliases xb+hb (both dead before adapt)
  unsigned short* wn = (unsigned short*)(ws + (size_t)16 * DHW * 2 + 4096);
  float* xi = (float*)(ws + (size_t)16 * DHW * 2 + 4096 +
                       (size_t)27 * DHW * 2 + 8192);
  unsigned short* Wpack2 =
      (unsigned short*)((char*)xi + (size_t)8 * DHW * 4 + 16384);
  unsigned short* Wpack1 = Wpack2 + 9216;

  dim3 blk(256);
  dim3 blk512(512);
  k_prep<<<55, blk, 0, stream>>>(w1, w2, Wpack2, Wpack1, ti, xi);
  k_xpose<<<DHW / 256, blk, 0, stream>>>(x, xb, xi);
  k_conv1m<<<128 * 64, blk, 0, stream>>>(xb, Wpack1, b1, hb);
  k_conv2<<<128 * 64, blk, 0, stream>>>(hb, Wpack2, wn);
  // adaptive ping-pong on interleaved fp32: xi -> ti -> xi -> out (planar)
  k_adapt6<0><<<64 * 64, blk512, 0, stream>>>(xi, wn, ti);
  k_adapt6<0><<<64 * 64, blk512, 0, stream>>>(ti, wn, xi);
  k_adapt6<1><<<64 * 64, blk512, 0, stream>>>(xi, wn, out);
}